// Round 10
// baseline (447.069 us; speedup 1.0000x reference)
//
#include <hip/hip_runtime.h>
#include <hip/hip_bf16.h>
#include <math.h>

#define NB 32
#define NS 2048
#define ND 8
#define NH 256
#define NK 1792      // 7*NH
#define NO 256
#define NM (NB*NS)   // 65536
#define WSTEP 0.03125f
#define CCH 64            // chunks over time
#define LCH (NS/CCH)      // 32 steps per chunk

typedef __attribute__((ext_vector_type(8))) short short8;
typedef __attribute__((ext_vector_type(4))) float f32x4;

// inter-pass scratch (static device globals; fully rewritten every call)
__device__ float g_ssum[NB*CCH*NH];
__device__ float g_wb0 [NB*CCH*NH];
__device__ float g_esum[NB*CCH*NH];
__device__ float g_ph0 [NB*CCH*NH];
__device__ float g_rep [NB*NS];
__device__ unsigned short g_bb[NO*NK];   // Wr in bf16, [col][k]

__device__ __forceinline__ unsigned short bf16_rn(float f){
    union { float f; unsigned int u; } v; v.f = f;
    unsigned int u = v.u;
    unsigned int r = (u + 0x7FFFu + ((u >> 16) & 1u)) >> 16;
    return (unsigned short)r;
}

// ---- pass 1: delta[t][b][h], rep[b][t], chunk s-sums ---------------------------
extern "C" __global__ __launch_bounds__(256)
void k_delta(const float* __restrict__ x, const float* __restrict__ We,
             const float* __restrict__ be, float* __restrict__ delta){
    int blk = blockIdx.x;
    int b = blk >> 6;            // / CCH
    int c = blk & (CCH-1);
    int t0 = c * LCH;
    int h = threadIdx.x;
    __shared__ float xs[(LCH+1)*ND];   // x rows t0-1 .. t0+LCH-1
    __shared__ float rep[LCH];

    for(int i = h; i < (LCH+1)*ND/4; i += 256){
        int row  = i >> 1;
        int col4 = (i & 1) * 4;
        int t = t0 - 1 + row; if(t < 0) t = 0;
        *(float4*)&xs[row*ND + col4] = *(const float4*)&x[((size_t)b*NS + t)*ND + col4];
    }
    __syncthreads();
    if(h < LCH){
        int t = t0 + h;
        float fl = 0.f;
        if(t > 0){
            bool eq = true;
            #pragma unroll
            for(int d2 = 0; d2 < ND; ++d2) eq = eq && (xs[(h+1)*ND+d2] == xs[h*ND+d2]);
            fl = eq ? 1.f : 0.f;
        }
        rep[h] = fl;
        g_rep[b*NS + t] = fl;
    }
    __syncthreads();

    float4 w0 = *(const float4*)&We[h*ND];
    float4 w1 = *(const float4*)&We[h*ND + 4];
    float bh = be[h];
    float ssum = 0.f;
    for(int j = 0; j < LCH; ++j){
        const float* xr = &xs[(j+1)*ND];
        float pt = bh + xr[0]*w0.x + xr[1]*w0.y + xr[2]*w0.z + xr[3]*w0.w
                      + xr[4]*w1.x + xr[5]*w1.y + xr[6]*w1.z + xr[7]*w1.w;
        float s, cc;
        sincosf(pt, &s, &cc);
        float d = atan2f(s, cc);
        delta[((size_t)(t0+j)*NB + b)*NH + h] = d;
        ssum += WSTEP + rep[j]*d;
    }
    g_ssum[(b*CCH + c)*NH + h] = ssum;
}

// ---- pass 2/4: exclusive prefix over chunks per (b,h) --------------------------
extern "C" __global__ __launch_bounds__(256)
void k_prefix_s(){
    int g = blockIdx.x*256 + threadIdx.x;   // 8192
    int b = g >> 8, h = g & 255;
    float acc = 0.f;
    for(int c = 0; c < CCH; ++c){
        size_t idx = ((size_t)(b*CCH + c))*NH + h;
        g_wb0[idx] = acc;
        acc += g_ssum[idx];
    }
}
extern "C" __global__ __launch_bounds__(256)
void k_prefix_e(){
    int g = blockIdx.x*256 + threadIdx.x;
    int b = g >> 8, h = g & 255;
    float acc = 0.f;
    for(int c = 0; c < CCH; ++c){
        size_t idx = ((size_t)(b*CCH + c))*NH + h;
        g_ph0[idx] = acc;
        acc += g_esum[idx];
    }
}

// ---- pass 3: within-chunk scan, write wb_hist, emit chunk e-sums ---------------
extern "C" __global__ __launch_bounds__(256)
void k_escan(const float* __restrict__ delta, float* __restrict__ wb_hist){
    int blk = blockIdx.x;
    int b = blk >> 6, c = blk & (CCH-1), t0 = c*LCH, h = threadIdx.x;
    __shared__ float rep[LCH];
    if(h < LCH) rep[h] = g_rep[b*NS + t0 + h];
    __syncthreads();
    float wb = g_wb0[(b*CCH + c)*NH + h];
    const float* dp = delta + (size_t)t0*NB*NH + b*NH + h;
    float* wp = wb_hist + ((size_t)b*NS + t0)*NH + h;
    float d[LCH];
    #pragma unroll
    for(int j = 0; j < LCH; ++j) d[j] = dp[(size_t)j*(NB*NH)];
    float esum = 0.f;
    #pragma unroll
    for(int j = 0; j < LCH; ++j){
        float wb2 = wb + WSTEP;
        float e = d[j] - sinf(wb2);
        esum += e;
        wb = wb2 + rep[j]*d[j];
        wp[(size_t)j*NH] = wb;
    }
    g_esum[(b*CCH + c)*NH + h] = esum;
}

// ---- pass 5: recompute e (bitwise-identical), write ph_hist --------------------
extern "C" __global__ __launch_bounds__(256)
void k_phw(const float* __restrict__ delta, float* __restrict__ ph_hist){
    int blk = blockIdx.x;
    int b = blk >> 6, c = blk & (CCH-1), t0 = c*LCH, h = threadIdx.x;
    __shared__ float rep[LCH];
    if(h < LCH) rep[h] = g_rep[b*NS + t0 + h];
    __syncthreads();
    float wb = g_wb0[(b*CCH + c)*NH + h];
    float ph = g_ph0[(b*CCH + c)*NH + h];
    const float* dp = delta + (size_t)t0*NB*NH + b*NH + h;
    float* pp = ph_hist + ((size_t)b*NS + t0)*NH + h;
    float d[LCH];
    #pragma unroll
    for(int j = 0; j < LCH; ++j) d[j] = dp[(size_t)j*(NB*NH)];
    #pragma unroll
    for(int j = 0; j < LCH; ++j){
        float wb2 = wb + WSTEP;
        float e = d[j] - sinf(wb2);
        ph += e;
        wb = wb2 + rep[j]*d[j];
        pp[(size_t)j*NH] = ph;
    }
}

// ---- pass 0b: Wr fp32 -> bf16 once ---------------------------------------------
extern "C" __global__ __launch_bounds__(256)
void k_bconv(const float* __restrict__ Wr){
    int i = (blockIdx.x*256 + threadIdx.x) * 8;   // 8 elements/thread
    if(i >= NO*NK) return;
    float4 a = *(const float4*)&Wr[i];
    float4 b = *(const float4*)&Wr[i+4];
    union { unsigned int u[4]; uint4 v; } r;
    r.u[0] = (unsigned int)bf16_rn(a.x) | ((unsigned int)bf16_rn(a.y) << 16);
    r.u[1] = (unsigned int)bf16_rn(a.z) | ((unsigned int)bf16_rn(a.w) << 16);
    r.u[2] = (unsigned int)bf16_rn(b.x) | ((unsigned int)bf16_rn(b.y) << 16);
    r.u[3] = (unsigned int)bf16_rn(b.z) | ((unsigned int)bf16_rn(b.w) << 16);
    *(uint4*)&g_bb[i] = r.v;
}

// ---- pass 6: logits — barrier-free, LDS-free, register A-generation ------------
// Channel map: 0=cos(ph) 1=sin(ph) 2=cos(ph/2) 3=sin(ph/2) 4=cos(wb) 5=sin(wb) 6=ph
#define DO_CH(CH, SRC) do{                                                        \
    short8 bfr[4];                                                                \
    _Pragma("unroll")                                                             \
    for(int nf = 0; nf < 4; ++nf)                                                 \
        bfr[nf] = *(const short8*)&g_bb[(size_t)(colb + nf*16)*NK + (CH)*256 + hb];\
    short8 afr[4];                                                                \
    _Pragma("unroll")                                                             \
    for(int mf = 0; mf < 4; ++mf){                                                \
        union{ unsigned int u[4]; short8 s; } r_;                                 \
        _Pragma("unroll")                                                         \
        for(int j = 0; j < 4; ++j)                                                \
            r_.u[j] = (unsigned int)bf16_rn(SRC[mf][2*j])                         \
                    | ((unsigned int)bf16_rn(SRC[mf][2*j+1]) << 16);              \
        afr[mf] = r_.s;                                                           \
    }                                                                             \
    _Pragma("unroll")                                                             \
    for(int mf = 0; mf < 4; ++mf)                                                 \
        _Pragma("unroll")                                                         \
        for(int nf = 0; nf < 4; ++nf)                                             \
            acc[mf][nf] = __builtin_amdgcn_mfma_f32_16x16x32_bf16(                \
                afr[mf], bfr[nf], acc[mf][nf], 0, 0, 0);                          \
}while(0)

extern "C" __global__ __launch_bounds__(512, 2)
void k_logits(const float* __restrict__ ph_hist, const float* __restrict__ wb_hist,
              const float* __restrict__ br, float* __restrict__ logits){
    int tid  = threadIdx.x;
    int m0   = blockIdx.x * 128;
    int lane = tid & 63, wid = tid >> 6;
    int wm = wid >> 2, wn = wid & 3;
    int l15 = lane & 15, kg = lane >> 4;
    int row0 = m0 + wm*64 + l15;
    int colb = wn*64 + l15;

    f32x4 acc[4][4];
    f32x4 zz = {0.f, 0.f, 0.f, 0.f};
    #pragma unroll
    for(int i = 0; i < 4; ++i)
        #pragma unroll
        for(int j = 0; j < 4; ++j) acc[i][j] = zz;

    for(int hc = 0; hc < 8; ++hc){
        int hb = hc*32 + kg*8;               // this lane's 8-h slice
        float a0[4][8], s8[4][8], c8[4][8];

        // load ph rows (8 floats per mf) — ch6 consumes raw ph
        #pragma unroll
        for(int mf = 0; mf < 4; ++mf){
            const float* p = ph_hist + (size_t)(row0 + mf*16)*NH + hb;
            float4 x0 = *(const float4*)p;
            float4 x1 = *(const float4*)(p + 4);
            a0[mf][0]=x0.x; a0[mf][1]=x0.y; a0[mf][2]=x0.z; a0[mf][3]=x0.w;
            a0[mf][4]=x1.x; a0[mf][5]=x1.y; a0[mf][6]=x1.z; a0[mf][7]=x1.w;
        }
        DO_CH(6, a0);

        // half-angle trig: s8=sin(ph/2), c8=cos(ph/2)
        #pragma unroll
        for(int mf = 0; mf < 4; ++mf)
            #pragma unroll
            for(int j = 0; j < 8; ++j){
                float r = a0[mf][j] * 0.07957747154594767f;  // 0.5/(2*pi)
                r -= floorf(r);
                s8[mf][j] = __builtin_amdgcn_sinf(r);
                c8[mf][j] = __builtin_amdgcn_cosf(r);
            }
        DO_CH(2, c8);
        DO_CH(3, s8);

        // double-angle: cos(ph)=c^2-s^2, sin(ph)=2sc
        #pragma unroll
        for(int mf = 0; mf < 4; ++mf)
            #pragma unroll
            for(int j = 0; j < 8; ++j)
                a0[mf][j] = c8[mf][j]*c8[mf][j] - s8[mf][j]*s8[mf][j];
        DO_CH(0, a0);
        #pragma unroll
        for(int mf = 0; mf < 4; ++mf)
            #pragma unroll
            for(int j = 0; j < 8; ++j)
                a0[mf][j] = 2.f * s8[mf][j] * c8[mf][j];
        DO_CH(1, a0);

        // wb channels
        #pragma unroll
        for(int mf = 0; mf < 4; ++mf){
            const float* p = wb_hist + (size_t)(row0 + mf*16)*NH + hb;
            float4 x0 = *(const float4*)p;
            float4 x1 = *(const float4*)(p + 4);
            a0[mf][0]=x0.x; a0[mf][1]=x0.y; a0[mf][2]=x0.z; a0[mf][3]=x0.w;
            a0[mf][4]=x1.x; a0[mf][5]=x1.y; a0[mf][6]=x1.z; a0[mf][7]=x1.w;
        }
        #pragma unroll
        for(int mf = 0; mf < 4; ++mf)
            #pragma unroll
            for(int j = 0; j < 8; ++j){
                float r = a0[mf][j] * 0.15915494309189535f;  // 1/(2*pi)
                r -= floorf(r);
                s8[mf][j] = __builtin_amdgcn_sinf(r);
                c8[mf][j] = __builtin_amdgcn_cosf(r);
            }
        DO_CH(4, c8);
        DO_CH(5, s8);
    }

    // epilogue
    int lg = kg;
    #pragma unroll
    for(int nf = 0; nf < 4; ++nf){
        int col = wn*64 + nf*16 + l15;
        float bias = br[col];
        #pragma unroll
        for(int mf = 0; mf < 4; ++mf){
            int row = m0 + wm*64 + mf*16 + lg*4;
            #pragma unroll
            for(int r = 0; r < 4; ++r)
                logits[(size_t)(row + r)*NO + col] = acc[mf][nf][r] + bias;
        }
    }
}

// ---- launcher ------------------------------------------------------------------
extern "C" void kernel_launch(void* const* d_in, const int* in_sizes, int n_in,
                              void* d_out, int out_size, void* d_ws, size_t ws_size,
                              hipStream_t stream){
    const float* x  = (const float*)d_in[0];
    const float* We = (const float*)d_in[1];
    const float* be = (const float*)d_in[2];
    const float* Wr = (const float*)d_in[3];
    const float* br = (const float*)d_in[4];

    float* logits = (float*)d_out;
    float* ph     = logits + (size_t)NM*NO;
    float* wb     = ph + (size_t)NM*NH;
    float* delta  = logits;   // reuse logits region as delta scratch [t][b][h]

    hipLaunchKernelGGL(k_bconv,    dim3((NO*NK/8 + 255)/256), dim3(256), 0, stream, Wr);
    hipLaunchKernelGGL(k_delta,    dim3(NB*CCH), dim3(256), 0, stream, x, We, be, delta);
    hipLaunchKernelGGL(k_prefix_s, dim3(32),     dim3(256), 0, stream);
    hipLaunchKernelGGL(k_escan,    dim3(NB*CCH), dim3(256), 0, stream, delta, wb);
    hipLaunchKernelGGL(k_prefix_e, dim3(32),     dim3(256), 0, stream);
    hipLaunchKernelGGL(k_phw,      dim3(NB*CCH), dim3(256), 0, stream, delta, ph);
    hipLaunchKernelGGL(k_logits,   dim3(NM/128), dim3(512), 0, stream, ph, wb, br, logits);
}

// Round 11
// 415.414 us; speedup vs baseline: 1.0762x; 1.0762x over previous
//
#include <hip/hip_runtime.h>
#include <hip/hip_bf16.h>
#include <math.h>

#define NB 32
#define NS 2048
#define ND 8
#define NH 256
#define NK 1792      // 7*NH
#define NO 256
#define NM (NB*NS)   // 65536
#define WSTEP 0.03125f
#define CCH 64            // chunks over time
#define LCH (NS/CCH)      // 32 steps per chunk

typedef __attribute__((ext_vector_type(8))) short short8;
typedef __attribute__((ext_vector_type(4))) float f32x4;

// inter-pass scratch (static device globals; fully rewritten every call)
__device__ float g_ssum[NB*CCH*NH];
__device__ float g_wb0 [NB*CCH*NH];
__device__ float g_esum[NB*CCH*NH];
__device__ float g_ph0 [NB*CCH*NH];
__device__ float g_rep [NB*NS];
__device__ unsigned short g_bb[NO*NK];   // Wr in bf16, [col][k]

__device__ __forceinline__ unsigned short bf16_rn(float f){
    union { float f; unsigned int u; } v; v.f = f;
    unsigned int u = v.u;
    unsigned int r = (u + 0x7FFFu + ((u >> 16) & 1u)) >> 16;
    return (unsigned short)r;
}

// ---- pass 1: delta[t][b][h], rep[b][t], chunk s-sums ---------------------------
extern "C" __global__ __launch_bounds__(256)
void k_delta(const float* __restrict__ x, const float* __restrict__ We,
             const float* __restrict__ be, float* __restrict__ delta){
    int blk = blockIdx.x;
    int b = blk >> 6;            // / CCH
    int c = blk & (CCH-1);
    int t0 = c * LCH;
    int h = threadIdx.x;
    __shared__ float xs[(LCH+1)*ND];   // x rows t0-1 .. t0+LCH-1
    __shared__ float rep[LCH];

    for(int i = h; i < (LCH+1)*ND/4; i += 256){
        int row  = i >> 1;
        int col4 = (i & 1) * 4;
        int t = t0 - 1 + row; if(t < 0) t = 0;
        *(float4*)&xs[row*ND + col4] = *(const float4*)&x[((size_t)b*NS + t)*ND + col4];
    }
    __syncthreads();
    if(h < LCH){
        int t = t0 + h;
        float fl = 0.f;
        if(t > 0){
            bool eq = true;
            #pragma unroll
            for(int d2 = 0; d2 < ND; ++d2) eq = eq && (xs[(h+1)*ND+d2] == xs[h*ND+d2]);
            fl = eq ? 1.f : 0.f;
        }
        rep[h] = fl;
        g_rep[b*NS + t] = fl;
    }
    __syncthreads();

    float4 w0 = *(const float4*)&We[h*ND];
    float4 w1 = *(const float4*)&We[h*ND + 4];
    float bh = be[h];
    float ssum = 0.f;
    for(int j = 0; j < LCH; ++j){
        const float* xr = &xs[(j+1)*ND];
        float pt = bh + xr[0]*w0.x + xr[1]*w0.y + xr[2]*w0.z + xr[3]*w0.w
                      + xr[4]*w1.x + xr[5]*w1.y + xr[6]*w1.z + xr[7]*w1.w;
        float s, cc;
        sincosf(pt, &s, &cc);
        float d = atan2f(s, cc);
        delta[((size_t)(t0+j)*NB + b)*NH + h] = d;
        ssum += WSTEP + rep[j]*d;
    }
    g_ssum[(b*CCH + c)*NH + h] = ssum;
}

// ---- pass 2/4: exclusive prefix over chunks per (b,h) --------------------------
extern "C" __global__ __launch_bounds__(256)
void k_prefix_s(){
    int g = blockIdx.x*256 + threadIdx.x;   // 8192
    int b = g >> 8, h = g & 255;
    float acc = 0.f;
    for(int c = 0; c < CCH; ++c){
        size_t idx = ((size_t)(b*CCH + c))*NH + h;
        g_wb0[idx] = acc;
        acc += g_ssum[idx];
    }
}
extern "C" __global__ __launch_bounds__(256)
void k_prefix_e(){
    int g = blockIdx.x*256 + threadIdx.x;
    int b = g >> 8, h = g & 255;
    float acc = 0.f;
    for(int c = 0; c < CCH; ++c){
        size_t idx = ((size_t)(b*CCH + c))*NH + h;
        g_ph0[idx] = acc;
        acc += g_esum[idx];
    }
}

// ---- pass 3: within-chunk scan, write wb_hist, emit chunk e-sums ---------------
extern "C" __global__ __launch_bounds__(256)
void k_escan(const float* __restrict__ delta, float* __restrict__ wb_hist){
    int blk = blockIdx.x;
    int b = blk >> 6, c = blk & (CCH-1), t0 = c*LCH, h = threadIdx.x;
    __shared__ float rep[LCH];
    if(h < LCH) rep[h] = g_rep[b*NS + t0 + h];
    __syncthreads();
    float wb = g_wb0[(b*CCH + c)*NH + h];
    const float* dp = delta + (size_t)t0*NB*NH + b*NH + h;
    float* wp = wb_hist + ((size_t)b*NS + t0)*NH + h;
    float d[LCH];
    #pragma unroll
    for(int j = 0; j < LCH; ++j) d[j] = dp[(size_t)j*(NB*NH)];
    float esum = 0.f;
    #pragma unroll
    for(int j = 0; j < LCH; ++j){
        float wb2 = wb + WSTEP;
        float e = d[j] - sinf(wb2);
        esum += e;
        wb = wb2 + rep[j]*d[j];
        wp[(size_t)j*NH] = wb;
    }
    g_esum[(b*CCH + c)*NH + h] = esum;
}

// ---- pass 5: recompute e (bitwise-identical), write ph_hist --------------------
extern "C" __global__ __launch_bounds__(256)
void k_phw(const float* __restrict__ delta, float* __restrict__ ph_hist){
    int blk = blockIdx.x;
    int b = blk >> 6, c = blk & (CCH-1), t0 = c*LCH, h = threadIdx.x;
    __shared__ float rep[LCH];
    if(h < LCH) rep[h] = g_rep[b*NS + t0 + h];
    __syncthreads();
    float wb = g_wb0[(b*CCH + c)*NH + h];
    float ph = g_ph0[(b*CCH + c)*NH + h];
    const float* dp = delta + (size_t)t0*NB*NH + b*NH + h;
    float* pp = ph_hist + ((size_t)b*NS + t0)*NH + h;
    float d[LCH];
    #pragma unroll
    for(int j = 0; j < LCH; ++j) d[j] = dp[(size_t)j*(NB*NH)];
    #pragma unroll
    for(int j = 0; j < LCH; ++j){
        float wb2 = wb + WSTEP;
        float e = d[j] - sinf(wb2);
        ph += e;
        wb = wb2 + rep[j]*d[j];
        pp[(size_t)j*NH] = ph;
    }
}

// ---- pass 0b: Wr fp32 -> bf16 once ---------------------------------------------
extern "C" __global__ __launch_bounds__(256)
void k_bconv(const float* __restrict__ Wr){
    int i = (blockIdx.x*256 + threadIdx.x) * 8;   // 8 elements/thread
    if(i >= NO*NK) return;
    float4 a = *(const float4*)&Wr[i];
    float4 b = *(const float4*)&Wr[i+4];
    union { unsigned int u[4]; uint4 v; } r;
    r.u[0] = (unsigned int)bf16_rn(a.x) | ((unsigned int)bf16_rn(a.y) << 16);
    r.u[1] = (unsigned int)bf16_rn(a.z) | ((unsigned int)bf16_rn(a.w) << 16);
    r.u[2] = (unsigned int)bf16_rn(b.x) | ((unsigned int)bf16_rn(b.y) << 16);
    r.u[3] = (unsigned int)bf16_rn(b.z) | ((unsigned int)bf16_rn(b.w) << 16);
    *(uint4*)&g_bb[i] = r.v;
}

// ---- pass 6: logits — A staged once per block in LDS, B direct from L2 ---------
// K-order channel-major: ks = c*8 + hseg;  k_global = c*256 + hseg*32
// channels: 0=cos(ph) 1=sin(ph) 2=cos(ph/2) 3=sin(ph/2) 4=cos(wb) 5=sin(wb) 6=ph
extern "C" __global__ __launch_bounds__(512, 4)
void k_logits(const float* __restrict__ ph_hist, const float* __restrict__ wb_hist,
              const float* __restrict__ br, float* __restrict__ logits){
    __shared__ __align__(16) unsigned short Al[128][40];
    int tid  = threadIdx.x;
    int m0   = blockIdx.x * 128;
    int lane = tid & 63, wid = tid >> 6;
    int wm = wid >> 2, wn = wid & 3;
    int l15 = lane & 15, kg = lane >> 4;
    int colb = wn*64 + l15;
    int arow = tid >> 2, ah = (tid & 3) * 8;   // staging coords: 128 rows x 4x8 h

    f32x4 acc[4][4];
    f32x4 zz = {0.f, 0.f, 0.f, 0.f};
    #pragma unroll
    for(int i = 0; i < 4; ++i)
        #pragma unroll
        for(int j = 0; j < 4; ++j) acc[i][j] = zz;

    for(int ks = 0; ks < 56; ++ks){
        int c    = ks >> 3;          // channel (uniform, scalar)
        int kcol = (ks & 7) * 32;    // h-segment base

        // ---- compute this thread's 8 A-values (pre-barrier: overlaps prev MFMA)
        const float* src = (c == 4 || c == 5) ? wb_hist : ph_hist;
        const float* p = src + (size_t)(m0 + arow)*NH + kcol + ah;
        float4 x0 = *(const float4*)p;
        float4 x1 = *(const float4*)(p + 4);
        float v[8] = {x0.x, x0.y, x0.z, x0.w, x1.x, x1.y, x1.z, x1.w};
        if(c != 6){
            float sc = (c == 2 || c == 3) ? 0.07957747154594767f
                                          : 0.15915494309189535f;   // (0.5)/2pi : 1/2pi
            bool is_sin = (c & 1);
            #pragma unroll
            for(int j = 0; j < 8; ++j){
                float r = v[j] * sc;
                r -= floorf(r);
                v[j] = is_sin ? __builtin_amdgcn_sinf(r) : __builtin_amdgcn_cosf(r);
            }
        }
        union { unsigned int u[4]; uint4 q; } pk;
        #pragma unroll
        for(int j = 0; j < 4; ++j)
            asm("v_cvt_pk_bf16_f32 %0, %1, %2"
                : "=v"(pk.u[j]) : "v"(v[2*j]), "v"(v[2*j+1]));

        // ---- B fragments from L2 (independent of LDS; issue early)
        short8 bfr[4];
        #pragma unroll
        for(int nf = 0; nf < 4; ++nf)
            bfr[nf] = *(const short8*)&g_bb[(size_t)(colb + nf*16)*NK + c*256 + kcol + kg*8];

        __syncthreads();                    // prev iteration's A-reads complete
        *(uint4*)&Al[arow][ah] = pk.q;
        __syncthreads();                    // A tile staged

        short8 afr[4];
        #pragma unroll
        for(int mf = 0; mf < 4; ++mf)
            afr[mf] = *(const short8*)&Al[wm*64 + mf*16 + l15][kg*8];
        #pragma unroll
        for(int mf = 0; mf < 4; ++mf)
            #pragma unroll
            for(int nf = 0; nf < 4; ++nf)
                acc[mf][nf] = __builtin_amdgcn_mfma_f32_16x16x32_bf16(
                    afr[mf], bfr[nf], acc[mf][nf], 0, 0, 0);
    }

    // epilogue
    #pragma unroll
    for(int nf = 0; nf < 4; ++nf){
        int col = wn*64 + nf*16 + l15;
        float bias = br[col];
        #pragma unroll
        for(int mf = 0; mf < 4; ++mf){
            int row = m0 + wm*64 + mf*16 + kg*4;
            #pragma unroll
            for(int r = 0; r < 4; ++r)
                logits[(size_t)(row + r)*NO + col] = acc[mf][nf][r] + bias;
        }
    }
}

// ---- launcher ------------------------------------------------------------------
extern "C" void kernel_launch(void* const* d_in, const int* in_sizes, int n_in,
                              void* d_out, int out_size, void* d_ws, size_t ws_size,
                              hipStream_t stream){
    const float* x  = (const float*)d_in[0];
    const float* We = (const float*)d_in[1];
    const float* be = (const float*)d_in[2];
    const float* Wr = (const float*)d_in[3];
    const float* br = (const float*)d_in[4];

    float* logits = (float*)d_out;
    float* ph     = logits + (size_t)NM*NO;
    float* wb     = ph + (size_t)NM*NH;
    float* delta  = logits;   // reuse logits region as delta scratch [t][b][h]

    hipLaunchKernelGGL(k_bconv,    dim3((NO*NK/8 + 255)/256), dim3(256), 0, stream, Wr);
    hipLaunchKernelGGL(k_delta,    dim3(NB*CCH), dim3(256), 0, stream, x, We, be, delta);
    hipLaunchKernelGGL(k_prefix_s, dim3(32),     dim3(256), 0, stream);
    hipLaunchKernelGGL(k_escan,    dim3(NB*CCH), dim3(256), 0, stream, delta, wb);
    hipLaunchKernelGGL(k_prefix_e, dim3(32),     dim3(256), 0, stream);
    hipLaunchKernelGGL(k_phw,      dim3(NB*CCH), dim3(256), 0, stream, delta, ph);
    hipLaunchKernelGGL(k_logits,   dim3(NM/128), dim3(512), 0, stream, ph, wb, br, logits);
}

// Round 12
// 400.825 us; speedup vs baseline: 1.1154x; 1.0364x over previous
//
#include <hip/hip_runtime.h>
#include <hip/hip_bf16.h>
#include <math.h>

#define NB 32
#define NS 2048
#define ND 8
#define NH 256
#define NK 1792      // 7*NH
#define NO 256
#define NM (NB*NS)   // 65536
#define WSTEP 0.03125f
#define CCH 64            // chunks over time
#define LCH (NS/CCH)      // 32 steps per chunk

typedef __attribute__((ext_vector_type(8))) short short8;
typedef __attribute__((ext_vector_type(4))) float f32x4;

// inter-pass scratch (static device globals; fully rewritten every call)
__device__ float g_ssum[NB*CCH*NH];
__device__ float g_wb0 [NB*CCH*NH];
__device__ float g_esum[NB*CCH*NH];
__device__ float g_ph0 [NB*CCH*NH];
__device__ float g_rep [NB*NS];
__device__ unsigned short g_bb[NO*NK];   // Wr in bf16, [col][k]

__device__ __forceinline__ unsigned short bf16_rn(float f){
    union { float f; unsigned int u; } v; v.f = f;
    unsigned int u = v.u;
    unsigned int r = (u + 0x7FFFu + ((u >> 16) & 1u)) >> 16;
    return (unsigned short)r;
}

// ---- pass 1: delta[t][b][h], rep[b][t], chunk s-sums ---------------------------
extern "C" __global__ __launch_bounds__(256)
void k_delta(const float* __restrict__ x, const float* __restrict__ We,
             const float* __restrict__ be, float* __restrict__ delta){
    int blk = blockIdx.x;
    int b = blk >> 6;            // / CCH
    int c = blk & (CCH-1);
    int t0 = c * LCH;
    int h = threadIdx.x;
    __shared__ float xs[(LCH+1)*ND];   // x rows t0-1 .. t0+LCH-1
    __shared__ float rep[LCH];

    for(int i = h; i < (LCH+1)*ND/4; i += 256){
        int row  = i >> 1;
        int col4 = (i & 1) * 4;
        int t = t0 - 1 + row; if(t < 0) t = 0;
        *(float4*)&xs[row*ND + col4] = *(const float4*)&x[((size_t)b*NS + t)*ND + col4];
    }
    __syncthreads();
    if(h < LCH){
        int t = t0 + h;
        float fl = 0.f;
        if(t > 0){
            bool eq = true;
            #pragma unroll
            for(int d2 = 0; d2 < ND; ++d2) eq = eq && (xs[(h+1)*ND+d2] == xs[h*ND+d2]);
            fl = eq ? 1.f : 0.f;
        }
        rep[h] = fl;
        g_rep[b*NS + t] = fl;
    }
    __syncthreads();

    float4 w0 = *(const float4*)&We[h*ND];
    float4 w1 = *(const float4*)&We[h*ND + 4];
    float bh = be[h];
    float ssum = 0.f;
    for(int j = 0; j < LCH; ++j){
        const float* xr = &xs[(j+1)*ND];
        float pt = bh + xr[0]*w0.x + xr[1]*w0.y + xr[2]*w0.z + xr[3]*w0.w
                      + xr[4]*w1.x + xr[5]*w1.y + xr[6]*w1.z + xr[7]*w1.w;
        float s, cc;
        sincosf(pt, &s, &cc);
        float d = atan2f(s, cc);
        delta[((size_t)(t0+j)*NB + b)*NH + h] = d;
        ssum += WSTEP + rep[j]*d;
    }
    g_ssum[(b*CCH + c)*NH + h] = ssum;
}

// ---- pass 2/4: exclusive prefix over chunks per (b,h) --------------------------
extern "C" __global__ __launch_bounds__(256)
void k_prefix_s(){
    int g = blockIdx.x*256 + threadIdx.x;   // 8192
    int b = g >> 8, h = g & 255;
    float acc = 0.f;
    for(int c = 0; c < CCH; ++c){
        size_t idx = ((size_t)(b*CCH + c))*NH + h;
        g_wb0[idx] = acc;
        acc += g_ssum[idx];
    }
}
extern "C" __global__ __launch_bounds__(256)
void k_prefix_e(){
    int g = blockIdx.x*256 + threadIdx.x;
    int b = g >> 8, h = g & 255;
    float acc = 0.f;
    for(int c = 0; c < CCH; ++c){
        size_t idx = ((size_t)(b*CCH + c))*NH + h;
        g_ph0[idx] = acc;
        acc += g_esum[idx];
    }
}

// ---- pass 3: within-chunk scan, write wb_hist, emit chunk e-sums ---------------
extern "C" __global__ __launch_bounds__(256)
void k_escan(const float* __restrict__ delta, float* __restrict__ wb_hist){
    int blk = blockIdx.x;
    int b = blk >> 6, c = blk & (CCH-1), t0 = c*LCH, h = threadIdx.x;
    __shared__ float rep[LCH];
    if(h < LCH) rep[h] = g_rep[b*NS + t0 + h];
    __syncthreads();
    float wb = g_wb0[(b*CCH + c)*NH + h];
    const float* dp = delta + (size_t)t0*NB*NH + b*NH + h;
    float* wp = wb_hist + ((size_t)b*NS + t0)*NH + h;
    float d[LCH];
    #pragma unroll
    for(int j = 0; j < LCH; ++j) d[j] = dp[(size_t)j*(NB*NH)];
    float esum = 0.f;
    #pragma unroll
    for(int j = 0; j < LCH; ++j){
        float wb2 = wb + WSTEP;
        float e = d[j] - sinf(wb2);
        esum += e;
        wb = wb2 + rep[j]*d[j];
        wp[(size_t)j*NH] = wb;
    }
    g_esum[(b*CCH + c)*NH + h] = esum;
}

// ---- pass 5: recompute e (bitwise-identical), write ph_hist --------------------
extern "C" __global__ __launch_bounds__(256)
void k_phw(const float* __restrict__ delta, float* __restrict__ ph_hist){
    int blk = blockIdx.x;
    int b = blk >> 6, c = blk & (CCH-1), t0 = c*LCH, h = threadIdx.x;
    __shared__ float rep[LCH];
    if(h < LCH) rep[h] = g_rep[b*NS + t0 + h];
    __syncthreads();
    float wb = g_wb0[(b*CCH + c)*NH + h];
    float ph = g_ph0[(b*CCH + c)*NH + h];
    const float* dp = delta + (size_t)t0*NB*NH + b*NH + h;
    float* pp = ph_hist + ((size_t)b*NS + t0)*NH + h;
    float d[LCH];
    #pragma unroll
    for(int j = 0; j < LCH; ++j) d[j] = dp[(size_t)j*(NB*NH)];
    #pragma unroll
    for(int j = 0; j < LCH; ++j){
        float wb2 = wb + WSTEP;
        float e = d[j] - sinf(wb2);
        ph += e;
        wb = wb2 + rep[j]*d[j];
        pp[(size_t)j*NH] = ph;
    }
}

// ---- pass 0b: Wr fp32 -> bf16 once ---------------------------------------------
extern "C" __global__ __launch_bounds__(256)
void k_bconv(const float* __restrict__ Wr){
    int i = (blockIdx.x*256 + threadIdx.x) * 8;   // 8 elements/thread
    if(i >= NO*NK) return;
    float4 a = *(const float4*)&Wr[i];
    float4 b = *(const float4*)&Wr[i+4];
    union { unsigned int u[4]; uint4 v; } r;
    r.u[0] = (unsigned int)bf16_rn(a.x) | ((unsigned int)bf16_rn(a.y) << 16);
    r.u[1] = (unsigned int)bf16_rn(a.z) | ((unsigned int)bf16_rn(a.w) << 16);
    r.u[2] = (unsigned int)bf16_rn(b.x) | ((unsigned int)bf16_rn(b.y) << 16);
    r.u[3] = (unsigned int)bf16_rn(b.z) | ((unsigned int)bf16_rn(b.w) << 16);
    *(uint4*)&g_bb[i] = r.v;
}

// ---- pass 6: logits — hseg-major, all 7 channels staged per segment ------------
// channels: 0=cos(ph) 1=sin(ph) 2=cos(ph/2) 3=sin(ph/2) 4=cos(wb) 5=sin(wb) 6=ph
#define LSTR 232   // LDS row stride in ushorts (464 B: 16B-aligned, 2-way read banks)
extern "C" __global__ __launch_bounds__(512, 4)
void k_logits(const float* __restrict__ ph_hist, const float* __restrict__ wb_hist,
              const float* __restrict__ br, float* __restrict__ logits){
    __shared__ __align__(16) unsigned short Al[128][LSTR];
    int tid  = threadIdx.x;
    int m0   = blockIdx.x * 128;
    int lane = tid & 63, wid = tid >> 6;
    int wm = wid >> 2, wn = wid & 3;
    int l15 = lane & 15, kg = lane >> 4;
    int colb = wn*64 + l15;
    int arow = tid >> 2, aq = (tid & 3) * 8;   // staging: row arow, 8 floats at seg-col aq

    f32x4 acc[4][4];
    f32x4 zz = {0.f, 0.f, 0.f, 0.f};
    #pragma unroll
    for(int i = 0; i < 4; ++i)
        #pragma unroll
        for(int j = 0; j < 4; ++j) acc[i][j] = zz;

    for(int hs = 0; hs < 8; ++hs){
        int hb = hs*32 + aq;
        // ---- load ph & wb once (8 floats each), compute all 7 channels
        const float* pp = ph_hist + (size_t)(m0 + arow)*NH + hb;
        const float* pw = wb_hist + (size_t)(m0 + arow)*NH + hb;
        float4 a0 = *(const float4*)pp;
        float4 a1 = *(const float4*)(pp + 4);
        float4 b0 = *(const float4*)pw;
        float4 b1 = *(const float4*)(pw + 4);
        float v[8] = {a0.x,a0.y,a0.z,a0.w, a1.x,a1.y,a1.z,a1.w};
        float w[8] = {b0.x,b0.y,b0.z,b0.w, b1.x,b1.y,b1.z,b1.w};

        unsigned int pk[7][4];
        float s2[8], c2[8];
        #pragma unroll
        for(int j = 0; j < 4; ++j)           // c6: raw ph
            asm("v_cvt_pk_bf16_f32 %0, %1, %2" : "=v"(pk[6][j]) : "v"(v[2*j]), "v"(v[2*j+1]));
        #pragma unroll
        for(int j = 0; j < 8; ++j){          // half-angle sincos
            float r = v[j] * 0.07957747154594767f;   // 0.5/(2pi)
            r -= floorf(r);
            s2[j] = __builtin_amdgcn_sinf(r);
            c2[j] = __builtin_amdgcn_cosf(r);
        }
        #pragma unroll
        for(int j = 0; j < 4; ++j){
            asm("v_cvt_pk_bf16_f32 %0, %1, %2" : "=v"(pk[2][j]) : "v"(c2[2*j]), "v"(c2[2*j+1]));
            asm("v_cvt_pk_bf16_f32 %0, %1, %2" : "=v"(pk[3][j]) : "v"(s2[2*j]), "v"(s2[2*j+1]));
        }
        #pragma unroll
        for(int j = 0; j < 8; ++j){          // double-angle: cos, sin of full ph
            float cv = (c2[j]-s2[j])*(c2[j]+s2[j]);
            float sv = 2.f*s2[j]*c2[j];
            s2[j] = cv; c2[j] = sv;          // reuse: s2=cos(ph), c2=sin(ph)
        }
        #pragma unroll
        for(int j = 0; j < 4; ++j){
            asm("v_cvt_pk_bf16_f32 %0, %1, %2" : "=v"(pk[0][j]) : "v"(s2[2*j]), "v"(s2[2*j+1]));
            asm("v_cvt_pk_bf16_f32 %0, %1, %2" : "=v"(pk[1][j]) : "v"(c2[2*j]), "v"(c2[2*j+1]));
        }
        #pragma unroll
        for(int j = 0; j < 8; ++j){          // wb sincos
            float r = w[j] * 0.15915494309189535f;   // 1/(2pi)
            r -= floorf(r);
            s2[j] = __builtin_amdgcn_sinf(r);
            c2[j] = __builtin_amdgcn_cosf(r);
        }
        #pragma unroll
        for(int j = 0; j < 4; ++j){
            asm("v_cvt_pk_bf16_f32 %0, %1, %2" : "=v"(pk[4][j]) : "v"(c2[2*j]), "v"(c2[2*j+1]));
            asm("v_cvt_pk_bf16_f32 %0, %1, %2" : "=v"(pk[5][j]) : "v"(s2[2*j]), "v"(s2[2*j+1]));
        }

        __syncthreads();                     // prev segment's LDS reads done
        #pragma unroll
        for(int c = 0; c < 7; ++c)
            *(uint4*)&Al[arow][c*32 + aq] = make_uint4(pk[c][0], pk[c][1], pk[c][2], pk[c][3]);
        __syncthreads();                     // tile staged

        // ---- 7 K-steps of MFMA from this segment
        #pragma unroll
        for(int c = 0; c < 7; ++c){
            short8 bfr[4];
            #pragma unroll
            for(int nf = 0; nf < 4; ++nf)
                bfr[nf] = *(const short8*)&g_bb[(size_t)(colb + nf*16)*NK + c*256 + hs*32 + kg*8];
            short8 afr[4];
            #pragma unroll
            for(int mf = 0; mf < 4; ++mf)
                afr[mf] = *(const short8*)&Al[wm*64 + mf*16 + l15][c*32 + kg*8];
            #pragma unroll
            for(int mf = 0; mf < 4; ++mf)
                #pragma unroll
                for(int nf = 0; nf < 4; ++nf)
                    acc[mf][nf] = __builtin_amdgcn_mfma_f32_16x16x32_bf16(
                        afr[mf], bfr[nf], acc[mf][nf], 0, 0, 0);
        }
    }

    // epilogue
    #pragma unroll
    for(int nf = 0; nf < 4; ++nf){
        int col = wn*64 + nf*16 + l15;
        float bias = br[col];
        #pragma unroll
        for(int mf = 0; mf < 4; ++mf){
            int row = m0 + wm*64 + mf*16 + kg*4;
            #pragma unroll
            for(int r = 0; r < 4; ++r)
                logits[(size_t)(row + r)*NO + col] = acc[mf][nf][r] + bias;
        }
    }
}

// ---- launcher ------------------------------------------------------------------
extern "C" void kernel_launch(void* const* d_in, const int* in_sizes, int n_in,
                              void* d_out, int out_size, void* d_ws, size_t ws_size,
                              hipStream_t stream){
    const float* x  = (const float*)d_in[0];
    const float* We = (const float*)d_in[1];
    const float* be = (const float*)d_in[2];
    const float* Wr = (const float*)d_in[3];
    const float* br = (const float*)d_in[4];

    float* logits = (float*)d_out;
    float* ph     = logits + (size_t)NM*NO;
    float* wb     = ph + (size_t)NM*NH;
    float* delta  = logits;   // reuse logits region as delta scratch [t][b][h]

    hipLaunchKernelGGL(k_bconv,    dim3((NO*NK/8 + 255)/256), dim3(256), 0, stream, Wr);
    hipLaunchKernelGGL(k_delta,    dim3(NB*CCH), dim3(256), 0, stream, x, We, be, delta);
    hipLaunchKernelGGL(k_prefix_s, dim3(32),     dim3(256), 0, stream);
    hipLaunchKernelGGL(k_escan,    dim3(NB*CCH), dim3(256), 0, stream, delta, wb);
    hipLaunchKernelGGL(k_prefix_e, dim3(32),     dim3(256), 0, stream);
    hipLaunchKernelGGL(k_phw,      dim3(NB*CCH), dim3(256), 0, stream, delta, ph);
    hipLaunchKernelGGL(k_logits,   dim3(NM/128), dim3(512), 0, stream, ph, wb, br, logits);
}

// Round 13
// 396.557 us; speedup vs baseline: 1.1274x; 1.0108x over previous
//
#include <hip/hip_runtime.h>
#include <hip/hip_bf16.h>
#include <math.h>

#define NB 32
#define NS 2048
#define ND 8
#define NH 256
#define NK 1792      // 7*NH
#define NO 256
#define NM (NB*NS)   // 65536
#define WSTEP 0.03125f
#define CCH 64            // chunks over time
#define LCH (NS/CCH)      // 32 steps per chunk

typedef __attribute__((ext_vector_type(8))) short short8;
typedef __attribute__((ext_vector_type(4))) float f32x4;

// inter-pass scratch (static device globals; fully rewritten every call)
__device__ float g_ssum[NB*CCH*NH];
__device__ float g_wb0 [NB*CCH*NH];
__device__ float g_esum[NB*CCH*NH];
__device__ float g_ph0 [NB*CCH*NH];
__device__ float g_rep [NB*NS];
__device__ unsigned short g_bb[NO*NK];   // Wr in bf16, [col][k]

__device__ __forceinline__ unsigned short bf16_rn(float f){
    union { float f; unsigned int u; } v; v.f = f;
    unsigned int u = v.u;
    unsigned int r = (u + 0x7FFFu + ((u >> 16) & 1u)) >> 16;
    return (unsigned short)r;
}

// ---- pass 1: delta[t][b][h], rep[b][t], chunk s-sums ---------------------------
extern "C" __global__ __launch_bounds__(256)
void k_delta(const float* __restrict__ x, const float* __restrict__ We,
             const float* __restrict__ be, float* __restrict__ delta){
    int blk = blockIdx.x;
    int b = blk >> 6;            // / CCH
    int c = blk & (CCH-1);
    int t0 = c * LCH;
    int h = threadIdx.x;
    __shared__ float xs[(LCH+1)*ND];   // x rows t0-1 .. t0+LCH-1
    __shared__ float rep[LCH];

    for(int i = h; i < (LCH+1)*ND/4; i += 256){
        int row  = i >> 1;
        int col4 = (i & 1) * 4;
        int t = t0 - 1 + row; if(t < 0) t = 0;
        *(float4*)&xs[row*ND + col4] = *(const float4*)&x[((size_t)b*NS + t)*ND + col4];
    }
    __syncthreads();
    if(h < LCH){
        int t = t0 + h;
        float fl = 0.f;
        if(t > 0){
            bool eq = true;
            #pragma unroll
            for(int d2 = 0; d2 < ND; ++d2) eq = eq && (xs[(h+1)*ND+d2] == xs[h*ND+d2]);
            fl = eq ? 1.f : 0.f;
        }
        rep[h] = fl;
        g_rep[b*NS + t] = fl;
    }
    __syncthreads();

    float4 w0 = *(const float4*)&We[h*ND];
    float4 w1 = *(const float4*)&We[h*ND + 4];
    float bh = be[h];
    float ssum = 0.f;
    for(int j = 0; j < LCH; ++j){
        const float* xr = &xs[(j+1)*ND];
        float pt = bh + xr[0]*w0.x + xr[1]*w0.y + xr[2]*w0.z + xr[3]*w0.w
                      + xr[4]*w1.x + xr[5]*w1.y + xr[6]*w1.z + xr[7]*w1.w;
        float s, cc;
        sincosf(pt, &s, &cc);
        float d = atan2f(s, cc);
        delta[((size_t)(t0+j)*NB + b)*NH + h] = d;
        ssum += WSTEP + rep[j]*d;
    }
    g_ssum[(b*CCH + c)*NH + h] = ssum;
}

// ---- pass 2/4: exclusive prefix over chunks per (b,h) --------------------------
extern "C" __global__ __launch_bounds__(256)
void k_prefix_s(){
    int g = blockIdx.x*256 + threadIdx.x;   // 8192
    int b = g >> 8, h = g & 255;
    float acc = 0.f;
    for(int c = 0; c < CCH; ++c){
        size_t idx = ((size_t)(b*CCH + c))*NH + h;
        g_wb0[idx] = acc;
        acc += g_ssum[idx];
    }
}
extern "C" __global__ __launch_bounds__(256)
void k_prefix_e(){
    int g = blockIdx.x*256 + threadIdx.x;
    int b = g >> 8, h = g & 255;
    float acc = 0.f;
    for(int c = 0; c < CCH; ++c){
        size_t idx = ((size_t)(b*CCH + c))*NH + h;
        g_ph0[idx] = acc;
        acc += g_esum[idx];
    }
}

// ---- pass 3: within-chunk scan, write wb_hist, emit chunk e-sums ---------------
extern "C" __global__ __launch_bounds__(256)
void k_escan(const float* __restrict__ delta, float* __restrict__ wb_hist){
    int blk = blockIdx.x;
    int b = blk >> 6, c = blk & (CCH-1), t0 = c*LCH, h = threadIdx.x;
    __shared__ float rep[LCH];
    if(h < LCH) rep[h] = g_rep[b*NS + t0 + h];
    __syncthreads();
    float wb = g_wb0[(b*CCH + c)*NH + h];
    const float* dp = delta + (size_t)t0*NB*NH + b*NH + h;
    float* wp = wb_hist + ((size_t)b*NS + t0)*NH + h;
    float d[LCH];
    #pragma unroll
    for(int j = 0; j < LCH; ++j) d[j] = dp[(size_t)j*(NB*NH)];
    float esum = 0.f;
    #pragma unroll
    for(int j = 0; j < LCH; ++j){
        float wb2 = wb + WSTEP;
        float e = d[j] - sinf(wb2);
        esum += e;
        wb = wb2 + rep[j]*d[j];
        wp[(size_t)j*NH] = wb;
    }
    g_esum[(b*CCH + c)*NH + h] = esum;
}

// ---- pass 5: recompute e (bitwise-identical), write ph_hist --------------------
extern "C" __global__ __launch_bounds__(256)
void k_phw(const float* __restrict__ delta, float* __restrict__ ph_hist){
    int blk = blockIdx.x;
    int b = blk >> 6, c = blk & (CCH-1), t0 = c*LCH, h = threadIdx.x;
    __shared__ float rep[LCH];
    if(h < LCH) rep[h] = g_rep[b*NS + t0 + h];
    __syncthreads();
    float wb = g_wb0[(b*CCH + c)*NH + h];
    float ph = g_ph0[(b*CCH + c)*NH + h];
    const float* dp = delta + (size_t)t0*NB*NH + b*NH + h;
    float* pp = ph_hist + ((size_t)b*NS + t0)*NH + h;
    float d[LCH];
    #pragma unroll
    for(int j = 0; j < LCH; ++j) d[j] = dp[(size_t)j*(NB*NH)];
    #pragma unroll
    for(int j = 0; j < LCH; ++j){
        float wb2 = wb + WSTEP;
        float e = d[j] - sinf(wb2);
        ph += e;
        wb = wb2 + rep[j]*d[j];
        pp[(size_t)j*NH] = ph;
    }
}

// ---- pass 0b: Wr fp32 -> bf16 once ---------------------------------------------
extern "C" __global__ __launch_bounds__(256)
void k_bconv(const float* __restrict__ Wr){
    int i = (blockIdx.x*256 + threadIdx.x) * 8;   // 8 elements/thread
    if(i >= NO*NK) return;
    float4 a = *(const float4*)&Wr[i];
    float4 b = *(const float4*)&Wr[i+4];
    union { unsigned int u[4]; uint4 v; } r;
    r.u[0] = (unsigned int)bf16_rn(a.x) | ((unsigned int)bf16_rn(a.y) << 16);
    r.u[1] = (unsigned int)bf16_rn(a.z) | ((unsigned int)bf16_rn(a.w) << 16);
    r.u[2] = (unsigned int)bf16_rn(b.x) | ((unsigned int)bf16_rn(b.y) << 16);
    r.u[3] = (unsigned int)bf16_rn(b.z) | ((unsigned int)bf16_rn(b.w) << 16);
    *(uint4*)&g_bb[i] = r.v;
}

// ---- pass 6: logits — 64-row blocks, 4 waves, 4 blocks/CU ----------------------
// channels: 0=cos(ph) 1=sin(ph) 2=cos(ph/2) 3=sin(ph/2) 4=cos(wb) 5=sin(wb) 6=ph
#define LSTR 232   // LDS row stride in ushorts (464 B: 16B-aligned rows)
extern "C" __global__ __launch_bounds__(256, 4)
void k_logits(const float* __restrict__ ph_hist, const float* __restrict__ wb_hist,
              const float* __restrict__ br, float* __restrict__ logits){
    __shared__ __align__(16) unsigned short Al[64][LSTR];
    int tid  = threadIdx.x;
    int m0   = blockIdx.x * 64;
    int lane = tid & 63, wn = tid >> 6;          // 4 waves: column groups
    int l15 = lane & 15, kg = lane >> 4;
    int colb = wn*64 + l15;
    int arow = tid >> 2, aq = (tid & 3) * 8;     // staging: 64 rows x 4x8 h

    f32x4 acc[4][4];
    f32x4 zz = {0.f, 0.f, 0.f, 0.f};
    #pragma unroll
    for(int i = 0; i < 4; ++i)
        #pragma unroll
        for(int j = 0; j < 4; ++j) acc[i][j] = zz;

    for(int hs = 0; hs < 8; ++hs){
        int hb = hs*32 + aq;
        // ---- load ph & wb once (8 floats each), compute all 7 channels
        const float* pp = ph_hist + (size_t)(m0 + arow)*NH + hb;
        const float* pw = wb_hist + (size_t)(m0 + arow)*NH + hb;
        float4 a0 = *(const float4*)pp;
        float4 a1 = *(const float4*)(pp + 4);
        float4 b0 = *(const float4*)pw;
        float4 b1 = *(const float4*)(pw + 4);
        float v[8] = {a0.x,a0.y,a0.z,a0.w, a1.x,a1.y,a1.z,a1.w};
        float w[8] = {b0.x,b0.y,b0.z,b0.w, b1.x,b1.y,b1.z,b1.w};

        unsigned int pk[7][4];
        float s2[8], c2[8];
        #pragma unroll
        for(int j = 0; j < 4; ++j)           // c6: raw ph
            asm("v_cvt_pk_bf16_f32 %0, %1, %2" : "=v"(pk[6][j]) : "v"(v[2*j]), "v"(v[2*j+1]));
        #pragma unroll
        for(int j = 0; j < 8; ++j){          // half-angle sincos
            float r = v[j] * 0.07957747154594767f;   // 0.5/(2pi)
            r -= floorf(r);
            s2[j] = __builtin_amdgcn_sinf(r);
            c2[j] = __builtin_amdgcn_cosf(r);
        }
        #pragma unroll
        for(int j = 0; j < 4; ++j){
            asm("v_cvt_pk_bf16_f32 %0, %1, %2" : "=v"(pk[2][j]) : "v"(c2[2*j]), "v"(c2[2*j+1]));
            asm("v_cvt_pk_bf16_f32 %0, %1, %2" : "=v"(pk[3][j]) : "v"(s2[2*j]), "v"(s2[2*j+1]));
        }
        #pragma unroll
        for(int j = 0; j < 8; ++j){          // double-angle: cos, sin of full ph
            float cv = (c2[j]-s2[j])*(c2[j]+s2[j]);
            float sv = 2.f*s2[j]*c2[j];
            s2[j] = cv; c2[j] = sv;          // reuse: s2=cos(ph), c2=sin(ph)
        }
        #pragma unroll
        for(int j = 0; j < 4; ++j){
            asm("v_cvt_pk_bf16_f32 %0, %1, %2" : "=v"(pk[0][j]) : "v"(s2[2*j]), "v"(s2[2*j+1]));
            asm("v_cvt_pk_bf16_f32 %0, %1, %2" : "=v"(pk[1][j]) : "v"(c2[2*j]), "v"(c2[2*j+1]));
        }
        #pragma unroll
        for(int j = 0; j < 8; ++j){          // wb sincos
            float r = w[j] * 0.15915494309189535f;   // 1/(2pi)
            r -= floorf(r);
            s2[j] = __builtin_amdgcn_sinf(r);
            c2[j] = __builtin_amdgcn_cosf(r);
        }
        #pragma unroll
        for(int j = 0; j < 4; ++j){
            asm("v_cvt_pk_bf16_f32 %0, %1, %2" : "=v"(pk[4][j]) : "v"(c2[2*j]), "v"(c2[2*j+1]));
            asm("v_cvt_pk_bf16_f32 %0, %1, %2" : "=v"(pk[5][j]) : "v"(s2[2*j]), "v"(s2[2*j+1]));
        }

        __syncthreads();                     // prev segment's LDS reads done
        #pragma unroll
        for(int c = 0; c < 7; ++c)
            *(uint4*)&Al[arow][c*32 + aq] = make_uint4(pk[c][0], pk[c][1], pk[c][2], pk[c][3]);
        __syncthreads();                     // tile staged

        // ---- 7 K-steps of MFMA from this segment
        #pragma unroll
        for(int c = 0; c < 7; ++c){
            short8 bfr[4];
            #pragma unroll
            for(int nf = 0; nf < 4; ++nf)
                bfr[nf] = *(const short8*)&g_bb[(size_t)(colb + nf*16)*NK + c*256 + hs*32 + kg*8];
            short8 afr[4];
            #pragma unroll
            for(int mf = 0; mf < 4; ++mf)
                afr[mf] = *(const short8*)&Al[mf*16 + l15][c*32 + kg*8];
            #pragma unroll
            for(int mf = 0; mf < 4; ++mf)
                #pragma unroll
                for(int nf = 0; nf < 4; ++nf)
                    acc[mf][nf] = __builtin_amdgcn_mfma_f32_16x16x32_bf16(
                        afr[mf], bfr[nf], acc[mf][nf], 0, 0, 0);
        }
    }

    // epilogue
    #pragma unroll
    for(int nf = 0; nf < 4; ++nf){
        int col = wn*64 + nf*16 + l15;
        float bias = br[col];
        #pragma unroll
        for(int mf = 0; mf < 4; ++mf){
            int row = m0 + mf*16 + kg*4;
            #pragma unroll
            for(int r = 0; r < 4; ++r)
                logits[(size_t)(row + r)*NO + col] = acc[mf][nf][r] + bias;
        }
    }
}

// ---- launcher ------------------------------------------------------------------
extern "C" void kernel_launch(void* const* d_in, const int* in_sizes, int n_in,
                              void* d_out, int out_size, void* d_ws, size_t ws_size,
                              hipStream_t stream){
    const float* x  = (const float*)d_in[0];
    const float* We = (const float*)d_in[1];
    const float* be = (const float*)d_in[2];
    const float* Wr = (const float*)d_in[3];
    const float* br = (const float*)d_in[4];

    float* logits = (float*)d_out;
    float* ph     = logits + (size_t)NM*NO;
    float* wb     = ph + (size_t)NM*NH;
    float* delta  = logits;   // reuse logits region as delta scratch [t][b][h]

    hipLaunchKernelGGL(k_bconv,    dim3((NO*NK/8 + 255)/256), dim3(256), 0, stream, Wr);
    hipLaunchKernelGGL(k_delta,    dim3(NB*CCH), dim3(256), 0, stream, x, We, be, delta);
    hipLaunchKernelGGL(k_prefix_s, dim3(32),     dim3(256), 0, stream);
    hipLaunchKernelGGL(k_escan,    dim3(NB*CCH), dim3(256), 0, stream, delta, wb);
    hipLaunchKernelGGL(k_prefix_e, dim3(32),     dim3(256), 0, stream);
    hipLaunchKernelGGL(k_phw,      dim3(NB*CCH), dim3(256), 0, stream, delta, ph);
    hipLaunchKernelGGL(k_logits,   dim3(NM/64),  dim3(256), 0, stream, ph, wb, br, logits);
}